// Round 1
// baseline (852.079 us; speedup 1.0000x reference)
//
#include <hip/hip_runtime.h>
#include <cstdint>

// ---------------------------------------------------------------------------
// GatedCrossAttention  (E=1024, Z=256, L=2048, B=8)
// Strategy: bf16 MFMA GEMMs (16x16x32) with fp32 accumulate, fused epilogues.
// ---------------------------------------------------------------------------

#define EN 1024
#define ZN 256
#define LN_ 2048
#define BN_ 8
#define MROWS (LN_ * BN_)          // 16384
#define QRU_N (2 * EN + ZN)        // 2304
#define LEN_SCALE 0.022097086912079608f  // 1/sqrt(2048)

typedef unsigned short u16;
typedef __bf16 bf16x8 __attribute__((ext_vector_type(8)));
typedef float f32x4 __attribute__((ext_vector_type(4)));

// ---- bf16 helpers (manual RNE, no hip_bf16 dependency) --------------------
__device__ __forceinline__ u16 f2bf(float f) {
    unsigned int u = __float_as_uint(f);
    u = (u + 0x7fff + ((u >> 16) & 1)) >> 16;
    return (u16)u;
}
__device__ __forceinline__ float bf2f(u16 s) {
    return __uint_as_float(((unsigned int)s) << 16);
}
__device__ __forceinline__ void store_bf16x4(u16* p, float a, float b, float c, float d) {
    union { u16 h[4]; uint2 v; } pk;
    pk.h[0] = f2bf(a); pk.h[1] = f2bf(b); pk.h[2] = f2bf(c); pk.h[3] = f2bf(d);
    *(uint2*)p = pk.v;
}

// ---- async global->LDS (16B/lane, wave-uniform LDS base + lane*16) --------
__device__ __forceinline__ void async_load16(const void* g, void* l) {
    __builtin_amdgcn_global_load_lds(
        (const __attribute__((address_space(1))) void*)g,
        (__attribute__((address_space(3))) void*)l,
        16, 0, 0);
}

// ---------------------------------------------------------------------------
// GEMM-BT: C[M,N] = A[M,K] @ B[N,K]^T, A/B bf16 row-major, epilogue functor.
// Block 256 (4 waves, 2x2), tile 128x128, BK=32, one 16x16x32 MFMA per k-step.
// Requires M%128==0, N%128==0, K%32==0.
// ---------------------------------------------------------------------------
template <typename Epi>
__global__ __launch_bounds__(256)
void gemm_bt(const u16* __restrict__ A, const u16* __restrict__ B,
             long long batchStrideA, long long batchStrideB, int K, Epi epi)
{
    __shared__ __align__(16) u16 As[128 * 32];
    __shared__ __align__(16) u16 Bs[128 * 32];

    const int tid  = threadIdx.x;
    const int lane = tid & 63;
    const int w    = tid >> 6;
    const int wm   = w >> 1, wn = w & 1;
    const int bz   = blockIdx.z;
    const long long m0 = (long long)blockIdx.y * 128;
    const long long n0 = (long long)blockIdx.x * 128;
    const u16* Ab = A + bz * batchStrideA;
    const u16* Bb = B + bz * batchStrideB;

    const int srow = lane >> 2;          // staging: row within 16-row group
    const int scol = (lane & 3) * 8;     // staging: element col (8 bf16 = 16B)
    const int quad = lane >> 4;
    const int l16  = lane & 15;

    const f32x4 fzero = {0.f, 0.f, 0.f, 0.f};
    f32x4 acc[4][4];
#pragma unroll
    for (int i = 0; i < 4; ++i)
#pragma unroll
        for (int j = 0; j < 4; ++j) acc[i][j] = fzero;

    for (int k0 = 0; k0 < K; k0 += 32) {
        __syncthreads();   // prior-iter LDS reads done before overwrite
#pragma unroll
        for (int t = 0; t < 2; ++t) {
            const int rbase = w * 32 + t * 16;
            async_load16(Ab + (m0 + rbase + srow) * K + (k0 + scol), (void*)&As[rbase * 32]);
            async_load16(Bb + (n0 + rbase + srow) * K + (k0 + scol), (void*)&Bs[rbase * 32]);
        }
        __builtin_amdgcn_s_waitcnt(0);
        __syncthreads();

        bf16x8 af[4], bfv[4];
#pragma unroll
        for (int mi = 0; mi < 4; ++mi)
            af[mi] = *(const bf16x8*)&As[(wm * 64 + mi * 16 + l16) * 32 + quad * 8];
#pragma unroll
        for (int ni = 0; ni < 4; ++ni)
            bfv[ni] = *(const bf16x8*)&Bs[(wn * 64 + ni * 16 + l16) * 32 + quad * 8];
#pragma unroll
        for (int mi = 0; mi < 4; ++mi)
#pragma unroll
            for (int ni = 0; ni < 4; ++ni)
                acc[mi][ni] = __builtin_amdgcn_mfma_f32_16x16x32_bf16(
                    af[mi], bfv[ni], acc[mi][ni], 0, 0, 0);
    }

    // epilogue: D[row][col], col = lane&15, row = quad*4 + reg  [verified m89/m91]
#pragma unroll
    for (int mi = 0; mi < 4; ++mi)
#pragma unroll
        for (int ni = 0; ni < 4; ++ni)
#pragma unroll
            for (int r = 0; r < 4; ++r) {
                int m = (int)m0 + wm * 64 + mi * 16 + quad * 4 + r;
                int n = (int)n0 + wn * 64 + ni * 16 + l16;
                epi(bz, m, n, acc[mi][ni][r]);
            }
}

// ---- epilogue functors -----------------------------------------------------
struct EpiRaw {            // kraw = key@Wk^T + bk   -> fp32 (16384 x 256)
    float* out; const float* bias;
    __device__ void operator()(int, int m, int n, float v) const {
        out[(long long)m * ZN + n] = v + bias[n];
    }
};
struct EpiQru {            // base = nq@Wqru^T + bqru; split q-raw / u / r
    float* qraw; u16* u; u16* r; const float* bqru;
    __device__ void operator()(int, int m, int n, float v) const {
        v += bqru[n];
        if (n < ZN) {
            qraw[(long long)m * ZN + n] = v;
        } else if (n < ZN + EN) {
            float s = 1.f / (1.f + __expf(-v));
            u[(long long)m * EN + (n - ZN)] = f2bf(s);
        } else {
            float s = v / (1.f + __expf(-v));
            r[(long long)m * EN + (n - ZN - EN)] = f2bf(s);
        }
    }
};
struct EpiV {              // v = silu(value@Wv^T + bv), stored (b, c, e) bf16
    u16* v; const float* bv;
    __device__ void operator()(int, int m, int n, float acc) const {
        float x = acc + bv[n];
        float s = x / (1.f + __expf(-x));
        int b = m & 7, c = m >> 3;
        v[((long long)b * LN_ + c) * EN + n] = f2bf(s);
    }
};
struct EpiQK {             // attn = relu(qk*scale + bias)^2, bf16 (b, s, c)
    u16* attn; const float* relpos;
    __device__ void operator()(int bz, int m, int n, float v) const {
        float val = v * LEN_SCALE + relpos[2047 + n - m];
        float t = fmaxf(val, 0.f);
        attn[(long long)bz * LN_ * LN_ + (long long)m * LN_ + n] = f2bf(t * t);
    }
};
struct EpiH {              // hr = (attn@v) * r, bf16 rows (s*8+b)
    u16* hr; const u16* r;
    __device__ void operator()(int bz, int m, int n, float acc) const {
        long long idx = ((long long)m * BN_ + bz) * EN + n;
        hr[idx] = f2bf(acc * bf2f(r[idx]));
    }
};
struct EpiOut {            // out = query + u*((hr@Wh^T + bh) - query), fp32
    float* out; const float* query; const u16* u; const float* bh;
    __device__ void operator()(int, int m, int n, float acc) const {
        long long idx = (long long)m * EN + n;
        float qv = query[idx];
        float uu = bf2f(u[idx]);
        out[idx] = qv + uu * ((acc + bh[n]) - qv);
    }
};

// ---------------------------------------------------------------------------
// prep: LN(query)->nq bf16; cast key_in, value -> bf16.  1 block per row.
// ---------------------------------------------------------------------------
__global__ __launch_bounds__(256)
void prep_kernel(const float* __restrict__ query, const float* __restrict__ key_in,
                 const float* __restrict__ value, const float* __restrict__ ln_w,
                 const float* __restrict__ ln_b,
                 u16* __restrict__ nq, u16* __restrict__ kin, u16* __restrict__ val)
{
    __shared__ float r1[4], r2[4];
    const int m = blockIdx.x, t = threadIdx.x;
    const long long base = (long long)m * EN + t * 4;
    float4 q = *(const float4*)(query + base);
    float a1 = q.x + q.y + q.z + q.w;
    float a2 = q.x * q.x + q.y * q.y + q.z * q.z + q.w * q.w;
#pragma unroll
    for (int o = 32; o; o >>= 1) { a1 += __shfl_down(a1, o, 64); a2 += __shfl_down(a2, o, 64); }
    if ((t & 63) == 0) { r1[t >> 6] = a1; r2[t >> 6] = a2; }
    __syncthreads();
    const float S1 = r1[0] + r1[1] + r1[2] + r1[3];
    const float S2 = r2[0] + r2[1] + r2[2] + r2[3];
    const float mu = S1 * (1.f / EN);
    const float var = S2 * (1.f / EN) - mu * mu;
    const float rstd = rsqrtf(var + 1e-5f);
    const int e = t * 4;
    float4 wv = *(const float4*)(ln_w + e);
    float4 bv = *(const float4*)(ln_b + e);
    store_bf16x4(nq + base, (q.x - mu) * rstd * wv.x + bv.x, (q.y - mu) * rstd * wv.y + bv.y,
                            (q.z - mu) * rstd * wv.z + bv.z, (q.w - mu) * rstd * wv.w + bv.w);
    float4 kq = *(const float4*)(key_in + base);
    store_bf16x4(kin + base, kq.x, kq.y, kq.z, kq.w);
    float4 vq = *(const float4*)(value + base);
    store_bf16x4(val + base, vq.x, vq.y, vq.z, vq.w);
}

// ---------------------------------------------------------------------------
// l2norm over Z=256 + scale/shift; raw (16384 x 256) fp32 -> out (b, s, z) bf16
// ---------------------------------------------------------------------------
__global__ __launch_bounds__(256)
void l2norm_scale(const float* __restrict__ raw, u16* __restrict__ out,
                  const float* __restrict__ gamma, const float* __restrict__ beta)
{
    __shared__ float red[4];
    const int m = blockIdx.x, z = threadIdx.x;
    const float x = raw[(long long)m * ZN + z];
    float ss = x * x;
#pragma unroll
    for (int o = 32; o; o >>= 1) ss += __shfl_down(ss, o, 64);
    if ((z & 63) == 0) red[z >> 6] = ss;
    __syncthreads();
    const float tot = red[0] + red[1] + red[2] + red[3];
    const float inv = 1.f / fmaxf(sqrtf(tot), 1e-5f);
    const float res = x * inv * (gamma[z] + 1.f) + beta[z];
    const int b = m & 7, s = m >> 3;
    out[((long long)b * LN_ + s) * ZN + z] = f2bf(res);
}

// ---------------------------------------------------------------------------
// transpose v (b, c, e) -> vT (b, e, c), bf16, 64x64 LDS tiles
// ---------------------------------------------------------------------------
__global__ __launch_bounds__(256)
void transpose_bc(const u16* __restrict__ v, u16* __restrict__ vT)
{
    __shared__ u16 tile[64][65];
    const int b = blockIdx.z;
    const int c0 = blockIdx.y * 64, e0 = blockIdx.x * 64;
    const int tx = threadIdx.x & 63, ty = threadIdx.x >> 6;
    const u16* src = v + (long long)b * LN_ * EN;
    u16* dst = vT + (long long)b * EN * LN_;
#pragma unroll
    for (int i = 0; i < 64; i += 4)
        tile[ty + i][tx] = src[(long long)(c0 + ty + i) * EN + (e0 + tx)];
    __syncthreads();
#pragma unroll
    for (int i = 0; i < 64; i += 4)
        dst[(long long)(e0 + ty + i) * LN_ + (c0 + tx)] = tile[tx][ty + i];
}

// ---------------------------------------------------------------------------
__global__ __launch_bounds__(256)
void castw(const float* __restrict__ in, u16* __restrict__ out, int n4)
{
    const int i = blockIdx.x * 256 + threadIdx.x;
    if (i < n4) {
        float4 x = ((const float4*)in)[i];
        store_bf16x4(out + (long long)i * 4, x.x, x.y, x.z, x.w);
    }
}

// ---------------------------------------------------------------------------
extern "C" void kernel_launch(void* const* d_in, const int* in_sizes, int n_in,
                              void* d_out, int out_size, void* d_ws, size_t ws_size,
                              hipStream_t stream)
{
    const float* query  = (const float*)d_in[0];
    const float* key_in = (const float*)d_in[1];
    const float* value  = (const float*)d_in[2];
    const float* ln_w   = (const float*)d_in[3];
    const float* ln_b   = (const float*)d_in[4];
    const float* Wv     = (const float*)d_in[5];
    const float* bv     = (const float*)d_in[6];
    const float* Wk     = (const float*)d_in[7];
    const float* bk     = (const float*)d_in[8];
    const float* Wqru   = (const float*)d_in[9];
    const float* bqru   = (const float*)d_in[10];
    const float* Wh     = (const float*)d_in[11];
    const float* bh     = (const float*)d_in[12];
    const float* gamma  = (const float*)d_in[13];
    const float* beta   = (const float*)d_in[14];
    const float* relpos = (const float*)d_in[15];
    float* out = (float*)d_out;

    char* ws = (char*)d_ws;
    const size_t MB = 1ull << 20;
    // region1 (0..64MB): nq | kin/vbce  -> later attn (full 64MB)
    u16*   nq    = (u16*)(ws + 0);          // 32 MiB, dead after GEMM-qru
    u16*   kin   = (u16*)(ws + 32 * MB);    // 32 MiB, dead after GEMM-k
    u16*   vbce  = (u16*)(ws + 32 * MB);    // 32 MiB (aliases kin), dead after transpose
    u16*   attn  = (u16*)(ws + 0);          // 64 MiB (aliases nq+kin/vbce)
    // region2 (64..96MB): val -> later hr
    u16*   valb  = (u16*)(ws + 64 * MB);    // 32 MiB, dead after GEMM-v
    u16*   hr    = (u16*)(ws + 64 * MB);    // 32 MiB (aliases valb)
    // persistent region (96MB..):
    u16*   qb    = (u16*)(ws + 96 * MB);    // 8 MiB  (b,s,z)
    u16*   kb    = (u16*)(ws + 104 * MB);   // 8 MiB  (b,c,z)
    u16*   ub    = (u16*)(ws + 112 * MB);   // 32 MiB
    u16*   rb    = (u16*)(ws + 144 * MB);   // 32 MiB
    u16*   vT    = (u16*)(ws + 176 * MB);   // 32 MiB (b,e,c)
    float* raw   = (float*)(ws + 208 * MB); // 16 MiB (shared by kraw then qraw)
    u16*   WqruB = (u16*)(ws + 224 * MB);   // 4.5 MiB
    u16*   WkB   = (u16*)(ws + 229 * MB);   // 0.5 MiB
    u16*   WvB   = (u16*)(ws + 230 * MB);   // 2 MiB
    u16*   WhB   = (u16*)(ws + 232 * MB);   // 2 MiB   (total 234 MiB)
    (void)ws_size; (void)in_sizes; (void)n_in; (void)out_size;

    // 1) cast weights to bf16
    castw<<<dim3(QRU_N * EN / 4 / 256), 256, 0, stream>>>(Wqru, WqruB, QRU_N * EN / 4);
    castw<<<dim3(ZN * EN / 4 / 256), 256, 0, stream>>>(Wk, WkB, ZN * EN / 4);
    castw<<<dim3(EN * EN / 4 / 256), 256, 0, stream>>>(Wv, WvB, EN * EN / 4);
    castw<<<dim3(EN * EN / 4 / 256), 256, 0, stream>>>(Wh, WhB, EN * EN / 4);

    // 2) layernorm(query) + bf16 casts of key/value
    prep_kernel<<<dim3(MROWS), 256, 0, stream>>>(query, key_in, value, ln_w, ln_b, nq, kin, valb);

    // 3) k = l2norm(key@Wk^T + bk)*g1 + beta1
    gemm_bt<<<dim3(ZN / 128, MROWS / 128, 1), 256, 0, stream>>>(
        kin, WkB, 0LL, 0LL, EN, EpiRaw{raw, bk});
    l2norm_scale<<<dim3(MROWS), 256, 0, stream>>>(raw, kb, gamma + ZN, beta + ZN);

    // 4) base = nq@Wqru^T + bqru -> qraw / u / r
    gemm_bt<<<dim3(QRU_N / 128, MROWS / 128, 1), 256, 0, stream>>>(
        nq, WqruB, 0LL, 0LL, EN, EpiQru{raw, ub, rb, bqru});
    l2norm_scale<<<dim3(MROWS), 256, 0, stream>>>(raw, qb, gamma, beta);

    // 5) v = silu(value@Wv^T + bv)  (b,c,e), then transpose to (b,e,c)
    gemm_bt<<<dim3(EN / 128, MROWS / 128, 1), 256, 0, stream>>>(
        valb, WvB, 0LL, 0LL, EN, EpiV{vbce, bv});
    transpose_bc<<<dim3(EN / 64, LN_ / 64, BN_), 256, 0, stream>>>(vbce, vT);

    // 6) attn = relu(q@k^T * scale + bias)^2   (batched over b)
    gemm_bt<<<dim3(LN_ / 128, LN_ / 128, BN_), 256, 0, stream>>>(
        qb, kb, (long long)LN_ * ZN, (long long)LN_ * ZN, ZN, EpiQK{attn, relpos});

    // 7) hr = (attn @ v) * r   (batched over b)
    gemm_bt<<<dim3(EN / 128, LN_ / 128, BN_), 256, 0, stream>>>(
        attn, vT, (long long)LN_ * LN_, (long long)EN * LN_, LN_, EpiH{hr, rb});

    // 8) out = query + u*((hr@Wh^T + bh) - query)
    gemm_bt<<<dim3(EN / 128, MROWS / 128, 1), 256, 0, stream>>>(
        hr, WhB, 0LL, 0LL, EN, EpiOut{out, query, ub, bh});
}

// Round 2
// 802.718 us; speedup vs baseline: 1.0615x; 1.0615x over previous
//
#include <hip/hip_runtime.h>
#include <cstdint>

// ---------------------------------------------------------------------------
// GatedCrossAttention  (E=1024, Z=256, L=2048, B=8)
// bf16 MFMA GEMMs (16x16x32), BK=64 K-loop, XOR-swizzled LDS, fused epilogues.
// ---------------------------------------------------------------------------

#define EN 1024
#define ZN 256
#define LN_ 2048
#define BN_ 8
#define MROWS (LN_ * BN_)          // 16384
#define QRU_N (2 * EN + ZN)        // 2304
#define LEN_SCALE 0.022097086912079608f  // 1/sqrt(2048)

typedef unsigned short u16;
typedef __bf16 bf16x8 __attribute__((ext_vector_type(8)));
typedef float f32x4 __attribute__((ext_vector_type(4)));

// ---- bf16 helpers ---------------------------------------------------------
__device__ __forceinline__ u16 f2bf(float f) {
    unsigned int u = __float_as_uint(f);
    u = (u + 0x7fff + ((u >> 16) & 1)) >> 16;
    return (u16)u;
}
__device__ __forceinline__ float bf2f(u16 s) {
    return __uint_as_float(((unsigned int)s) << 16);
}
__device__ __forceinline__ void store_bf16x4(u16* p, float a, float b, float c, float d) {
    union { u16 h[4]; uint2 v; } pk;
    pk.h[0] = f2bf(a); pk.h[1] = f2bf(b); pk.h[2] = f2bf(c); pk.h[3] = f2bf(d);
    *(uint2*)p = pk.v;
}

// ---- async global->LDS (16B/lane, wave-uniform LDS base + lane*16) --------
__device__ __forceinline__ void async_load16(const void* g, void* l) {
    __builtin_amdgcn_global_load_lds(
        (const __attribute__((address_space(1))) void*)g,
        (__attribute__((address_space(3))) void*)l,
        16, 0, 0);
}

// ---------------------------------------------------------------------------
// GEMM-BT: C[M,N] = A[M,K] @ B[N,K]^T, A/B bf16 row-major, epilogue functor.
// Block 256 (4 waves, 2x2 wave grid), tile 128x128, BK=64.
// LDS rows are 64 elems (128 B = all 32 banks); the 16B chunk index is
// XOR-swizzled by (row&7) so ds_read_b128 spreads 2 lanes/bank (free, m136).
// Swizzle is applied on the GLOBAL source address of global_load_lds (the
// LDS destination is hardware-fixed at base+lane*16) and undone on read.
// Requires M%128==0, N%128==0, K%64==0.
// ---------------------------------------------------------------------------
template <typename Epi>
__global__ __launch_bounds__(256)
void gemm_bt(const u16* __restrict__ A, const u16* __restrict__ B,
             long long batchStrideA, long long batchStrideB, int K, Epi epi)
{
    __shared__ __align__(16) u16 As[128 * 64];
    __shared__ __align__(16) u16 Bs[128 * 64];

    const int tid  = threadIdx.x;
    const int lane = tid & 63;
    const int w    = tid >> 6;
    const int wm   = w >> 1, wn = w & 1;
    const int bz   = blockIdx.z;
    const long long m0 = (long long)blockIdx.y * 128;
    const long long n0 = (long long)blockIdx.x * 128;
    const u16* Ab = A + bz * batchStrideA;
    const u16* Bb = B + bz * batchStrideB;

    // staging: lane covers row (lane>>3) of each 8-row group, swizzled chunk
    const int srow = lane >> 3;                          // 0..7
    const int scol = ((lane & 7) ^ srow) * 8;            // swizzled source col
    const int quad = lane >> 4;
    const int l16  = lane & 15;

    // read-side swizzled chunk offsets (elems), constant per lane
    const int choff0 = ((quad     ^ (l16 & 7)) * 8);     // k-half 0
    const int choff1 = (((4 + quad) ^ (l16 & 7)) * 8);   // k-half 1

    const f32x4 fzero = {0.f, 0.f, 0.f, 0.f};
    f32x4 acc[4][4];
#pragma unroll
    for (int i = 0; i < 4; ++i)
#pragma unroll
        for (int j = 0; j < 4; ++j) acc[i][j] = fzero;

    for (int k0 = 0; k0 < K; k0 += 64) {
        __syncthreads();   // prior-iter LDS reads done before overwrite
#pragma unroll
        for (int t = 0; t < 4; ++t) {
            const int rbase = w * 32 + t * 8;
            async_load16(Ab + (m0 + rbase + srow) * K + (k0 + scol), (void*)&As[rbase * 64]);
            async_load16(Bb + (n0 + rbase + srow) * K + (k0 + scol), (void*)&Bs[rbase * 64]);
        }
        __builtin_amdgcn_s_waitcnt(0);
        __syncthreads();

#pragma unroll
        for (int h = 0; h < 2; ++h) {
            const int ch = h ? choff1 : choff0;
            bf16x8 af[4], bfv[4];
#pragma unroll
            for (int mi = 0; mi < 4; ++mi)
                af[mi] = *(const bf16x8*)&As[(wm * 64 + mi * 16 + l16) * 64 + ch];
#pragma unroll
            for (int ni = 0; ni < 4; ++ni)
                bfv[ni] = *(const bf16x8*)&Bs[(wn * 64 + ni * 16 + l16) * 64 + ch];
#pragma unroll
            for (int mi = 0; mi < 4; ++mi)
#pragma unroll
                for (int ni = 0; ni < 4; ++ni)
                    acc[mi][ni] = __builtin_amdgcn_mfma_f32_16x16x32_bf16(
                        af[mi], bfv[ni], acc[mi][ni], 0, 0, 0);
        }
    }

    // epilogue: D[row][col], col = lane&15, row = quad*4 + reg  [verified m89/m91]
#pragma unroll
    for (int mi = 0; mi < 4; ++mi)
#pragma unroll
        for (int ni = 0; ni < 4; ++ni)
#pragma unroll
            for (int r = 0; r < 4; ++r) {
                int m = (int)m0 + wm * 64 + mi * 16 + quad * 4 + r;
                int n = (int)n0 + wn * 64 + ni * 16 + l16;
                epi(bz, m, n, acc[mi][ni][r]);
            }
}

// ---- epilogue functors -----------------------------------------------------
struct EpiRaw {            // kraw = key@Wk^T + bk   -> fp32 (16384 x 256)
    float* out; const float* bias;
    __device__ void operator()(int, int m, int n, float v) const {
        out[(long long)m * ZN + n] = v + bias[n];
    }
};
struct EpiQru {            // base = nq@Wqru^T + bqru; split q-raw / u / r
    float* qraw; u16* u; u16* r; const float* bqru;
    __device__ void operator()(int, int m, int n, float v) const {
        v += bqru[n];
        if (n < ZN) {
            qraw[(long long)m * ZN + n] = v;
        } else if (n < ZN + EN) {
            float s = 1.f / (1.f + __expf(-v));
            u[(long long)m * EN + (n - ZN)] = f2bf(s);
        } else {
            float s = v / (1.f + __expf(-v));
            r[(long long)m * EN + (n - ZN - EN)] = f2bf(s);
        }
    }
};
struct EpiV {              // v = silu(value@Wv^T + bv), stored (b, c, e) bf16
    u16* v; const float* bv;
    __device__ void operator()(int, int m, int n, float acc) const {
        float x = acc + bv[n];
        float s = x / (1.f + __expf(-x));
        int b = m & 7, c = m >> 3;
        v[((long long)b * LN_ + c) * EN + n] = f2bf(s);
    }
};
struct EpiQK {             // attn = relu(qk*scale + bias)^2, bf16 (b, s, c)
    u16* attn; const float* relpos;
    __device__ void operator()(int bz, int m, int n, float v) const {
        float val = v * LEN_SCALE + relpos[2047 + n - m];
        float t = fmaxf(val, 0.f);
        attn[(long long)bz * LN_ * LN_ + (long long)m * LN_ + n] = f2bf(t * t);
    }
};
struct EpiH {              // hr = (attn@v) * r, bf16 rows (s*8+b)
    u16* hr; const u16* r;
    __device__ void operator()(int bz, int m, int n, float acc) const {
        long long idx = ((long long)m * BN_ + bz) * EN + n;
        hr[idx] = f2bf(acc * bf2f(r[idx]));
    }
};
struct EpiOut {            // out = query + u*((hr@Wh^T + bh) - query), fp32
    float* out; const float* query; const u16* u; const float* bh;
    __device__ void operator()(int, int m, int n, float acc) const {
        long long idx = (long long)m * EN + n;
        float qv = query[idx];
        float uu = bf2f(u[idx]);
        out[idx] = qv + uu * ((acc + bh[n]) - qv);
    }
};

// ---------------------------------------------------------------------------
// prep: LN(query)->nq bf16; cast key_in, value -> bf16.  1 block per row.
// ---------------------------------------------------------------------------
__global__ __launch_bounds__(256)
void prep_kernel(const float* __restrict__ query, const float* __restrict__ key_in,
                 const float* __restrict__ value, const float* __restrict__ ln_w,
                 const float* __restrict__ ln_b,
                 u16* __restrict__ nq, u16* __restrict__ kin, u16* __restrict__ val)
{
    __shared__ float r1[4], r2[4];
    const int m = blockIdx.x, t = threadIdx.x;
    const long long base = (long long)m * EN + t * 4;
    float4 q = *(const float4*)(query + base);
    float a1 = q.x + q.y + q.z + q.w;
    float a2 = q.x * q.x + q.y * q.y + q.z * q.z + q.w * q.w;
#pragma unroll
    for (int o = 32; o; o >>= 1) { a1 += __shfl_down(a1, o, 64); a2 += __shfl_down(a2, o, 64); }
    if ((t & 63) == 0) { r1[t >> 6] = a1; r2[t >> 6] = a2; }
    __syncthreads();
    const float S1 = r1[0] + r1[1] + r1[2] + r1[3];
    const float S2 = r2[0] + r2[1] + r2[2] + r2[3];
    const float mu = S1 * (1.f / EN);
    const float var = S2 * (1.f / EN) - mu * mu;
    const float rstd = rsqrtf(var + 1e-5f);
    const int e = t * 4;
    float4 wv = *(const float4*)(ln_w + e);
    float4 bv = *(const float4*)(ln_b + e);
    store_bf16x4(nq + base, (q.x - mu) * rstd * wv.x + bv.x, (q.y - mu) * rstd * wv.y + bv.y,
                            (q.z - mu) * rstd * wv.z + bv.z, (q.w - mu) * rstd * wv.w + bv.w);
    float4 kq = *(const float4*)(key_in + base);
    store_bf16x4(kin + base, kq.x, kq.y, kq.z, kq.w);
    float4 vq = *(const float4*)(value + base);
    store_bf16x4(val + base, vq.x, vq.y, vq.z, vq.w);
}

// ---------------------------------------------------------------------------
// l2norm over Z=256 + scale/shift; raw (16384 x 256) fp32 -> out (b, s, z) bf16
// ---------------------------------------------------------------------------
__global__ __launch_bounds__(256)
void l2norm_scale(const float* __restrict__ raw, u16* __restrict__ out,
                  const float* __restrict__ gamma, const float* __restrict__ beta)
{
    __shared__ float red[4];
    const int m = blockIdx.x, z = threadIdx.x;
    const float x = raw[(long long)m * ZN + z];
    float ss = x * x;
#pragma unroll
    for (int o = 32; o; o >>= 1) ss += __shfl_down(ss, o, 64);
    if ((z & 63) == 0) red[z >> 6] = ss;
    __syncthreads();
    const float tot = red[0] + red[1] + red[2] + red[3];
    const float inv = 1.f / fmaxf(sqrtf(tot), 1e-5f);
    const float res = x * inv * (gamma[z] + 1.f) + beta[z];
    const int b = m & 7, s = m >> 3;
    out[((long long)b * LN_ + s) * ZN + z] = f2bf(res);
}

// ---------------------------------------------------------------------------
// transpose v (b, c, e) -> vT (b, e, c), bf16, 64x64 LDS tiles
// ---------------------------------------------------------------------------
__global__ __launch_bounds__(256)
void transpose_bc(const u16* __restrict__ v, u16* __restrict__ vT)
{
    __shared__ u16 tile[64][65];
    const int b = blockIdx.z;
    const int c0 = blockIdx.y * 64, e0 = blockIdx.x * 64;
    const int tx = threadIdx.x & 63, ty = threadIdx.x >> 6;
    const u16* src = v + (long long)b * LN_ * EN;
    u16* dst = vT + (long long)b * EN * LN_;
#pragma unroll
    for (int i = 0; i < 64; i += 4)
        tile[ty + i][tx] = src[(long long)(c0 + ty + i) * EN + (e0 + tx)];
    __syncthreads();
#pragma unroll
    for (int i = 0; i < 64; i += 4)
        dst[(long long)(e0 + ty + i) * LN_ + (c0 + tx)] = tile[tx][ty + i];
}

// ---------------------------------------------------------------------------
__global__ __launch_bounds__(256)
void castw(const float* __restrict__ in, u16* __restrict__ out, int n4)
{
    const int i = blockIdx.x * 256 + threadIdx.x;
    if (i < n4) {
        float4 x = ((const float4*)in)[i];
        store_bf16x4(out + (long long)i * 4, x.x, x.y, x.z, x.w);
    }
}

// ---------------------------------------------------------------------------
extern "C" void kernel_launch(void* const* d_in, const int* in_sizes, int n_in,
                              void* d_out, int out_size, void* d_ws, size_t ws_size,
                              hipStream_t stream)
{
    const float* query  = (const float*)d_in[0];
    const float* key_in = (const float*)d_in[1];
    const float* value  = (const float*)d_in[2];
    const float* ln_w   = (const float*)d_in[3];
    const float* ln_b   = (const float*)d_in[4];
    const float* Wv     = (const float*)d_in[5];
    const float* bv     = (const float*)d_in[6];
    const float* Wk     = (const float*)d_in[7];
    const float* bk     = (const float*)d_in[8];
    const float* Wqru   = (const float*)d_in[9];
    const float* bqru   = (const float*)d_in[10];
    const float* Wh     = (const float*)d_in[11];
    const float* bh     = (const float*)d_in[12];
    const float* gamma  = (const float*)d_in[13];
    const float* beta   = (const float*)d_in[14];
    const float* relpos = (const float*)d_in[15];
    float* out = (float*)d_out;

    char* ws = (char*)d_ws;
    const size_t MB = 1ull << 20;
    // region1 (0..64MB): nq | kin/vbce  -> later attn (full 64MB)
    u16*   nq    = (u16*)(ws + 0);          // 32 MiB, dead after GEMM-qru
    u16*   kin   = (u16*)(ws + 32 * MB);    // 32 MiB, dead after GEMM-k
    u16*   vbce  = (u16*)(ws + 32 * MB);    // 32 MiB (aliases kin), dead after transpose
    u16*   attn  = (u16*)(ws + 0);          // 64 MiB (aliases nq+kin/vbce)
    // region2 (64..96MB): val -> later hr
    u16*   valb  = (u16*)(ws + 64 * MB);    // 32 MiB, dead after GEMM-v
    u16*   hr    = (u16*)(ws + 64 * MB);    // 32 MiB (aliases valb)
    // persistent region (96MB..):
    u16*   qb    = (u16*)(ws + 96 * MB);    // 8 MiB  (b,s,z)
    u16*   kb    = (u16*)(ws + 104 * MB);   // 8 MiB  (b,c,z)
    u16*   ub    = (u16*)(ws + 112 * MB);   // 32 MiB
    u16*   rb    = (u16*)(ws + 144 * MB);   // 32 MiB
    u16*   vT    = (u16*)(ws + 176 * MB);   // 32 MiB (b,e,c)
    float* raw   = (float*)(ws + 208 * MB); // 16 MiB (shared by kraw then qraw)
    u16*   WqruB = (u16*)(ws + 224 * MB);   // 4.5 MiB
    u16*   WkB   = (u16*)(ws + 229 * MB);   // 0.5 MiB
    u16*   WvB   = (u16*)(ws + 230 * MB);   // 2 MiB
    u16*   WhB   = (u16*)(ws + 232 * MB);   // 2 MiB   (total 234 MiB)
    (void)ws_size; (void)in_sizes; (void)n_in; (void)out_size;

    // 1) cast weights to bf16
    castw<<<dim3(QRU_N * EN / 4 / 256), 256, 0, stream>>>(Wqru, WqruB, QRU_N * EN / 4);
    castw<<<dim3(ZN * EN / 4 / 256), 256, 0, stream>>>(Wk, WkB, ZN * EN / 4);
    castw<<<dim3(EN * EN / 4 / 256), 256, 0, stream>>>(Wv, WvB, EN * EN / 4);
    castw<<<dim3(EN * EN / 4 / 256), 256, 0, stream>>>(Wh, WhB, EN * EN / 4);

    // 2) layernorm(query) + bf16 casts of key/value
    prep_kernel<<<dim3(MROWS), 256, 0, stream>>>(query, key_in, value, ln_w, ln_b, nq, kin, valb);

    // 3) k = l2norm(key@Wk^T + bk)*g1 + beta1
    gemm_bt<<<dim3(ZN / 128, MROWS / 128, 1), 256, 0, stream>>>(
        kin, WkB, 0LL, 0LL, EN, EpiRaw{raw, bk});
    l2norm_scale<<<dim3(MROWS), 256, 0, stream>>>(raw, kb, gamma + ZN, beta + ZN);

    // 4) base = nq@Wqru^T + bqru -> qraw / u / r
    gemm_bt<<<dim3(QRU_N / 128, MROWS / 128, 1), 256, 0, stream>>>(
        nq, WqruB, 0LL, 0LL, EN, EpiQru{raw, ub, rb, bqru});
    l2norm_scale<<<dim3(MROWS), 256, 0, stream>>>(raw, qb, gamma, beta);

    // 5) v = silu(value@Wv^T + bv)  (b,c,e), then transpose to (b,e,c)
    gemm_bt<<<dim3(EN / 128, MROWS / 128, 1), 256, 0, stream>>>(
        valb, WvB, 0LL, 0LL, EN, EpiV{vbce, bv});
    transpose_bc<<<dim3(EN / 64, LN_ / 64, BN_), 256, 0, stream>>>(vbce, vT);

    // 6) attn = relu(q@k^T * scale + bias)^2   (batched over b)
    gemm_bt<<<dim3(LN_ / 128, LN_ / 128, BN_), 256, 0, stream>>>(
        qb, kb, (long long)LN_ * ZN, (long long)LN_ * ZN, ZN, EpiQK{attn, relpos});

    // 7) hr = (attn @ v) * r   (batched over b)
    gemm_bt<<<dim3(EN / 128, LN_ / 128, BN_), 256, 0, stream>>>(
        attn, vT, (long long)LN_ * LN_, (long long)EN * LN_, LN_, EpiH{hr, rb});

    // 8) out = query + u*((hr@Wh^T + bh) - query)
    gemm_bt<<<dim3(EN / 128, MROWS / 128, 1), 256, 0, stream>>>(
        hr, WhB, 0LL, 0LL, EN, EpiOut{out, query, ub, bh});
}